// Round 1
// baseline (181.187 us; speedup 1.0000x reference)
//
#include <hip/hip_runtime.h>
#include <hip/hip_bf16.h>

// cyclicLoss: out = mean((input-target)^2) + 0.1*sqrt( sum_{i<(N-1)*T} (input[i]-input[i+T])^2 )
// input/target: fp32, n = N*T = 2048*8192 = 16,777,216 elements (64 MB each).
// Memory-bound: ~128 MB from HBM (shifted input re-read hits L3). Roofline ~20 us.

#define LAMDA 0.1

__global__ __launch_bounds__(256) void cyclic_reduce_kernel(
    const float4* __restrict__ in4,
    const float4* __restrict__ tg4,
    const int* __restrict__ pT,
    const int* __restrict__ pN,
    long long n,           // total scalar elements
    double* __restrict__ ws)
{
    const int T = pT[0];
    const int N = pN[0];
    const long long n4 = n >> 2;                       // full float4 groups
    const long long limit = (long long)(N - 1) * (long long)T;  // diff region (scalars)
    const long long limit4 = limit >> 2;               // full float4 groups inside diff region
    const long long t4 = (long long)T >> 2;

    float mse_acc = 0.0f;
    float dif_acc = 0.0f;

    const long long stride = (long long)gridDim.x * blockDim.x;
    for (long long i = (long long)blockIdx.x * blockDim.x + threadIdx.x;
         i < n4; i += stride) {
        float4 a = in4[i];
        float4 b = tg4[i];
        float e0 = a.x - b.x, e1 = a.y - b.y, e2 = a.z - b.z, e3 = a.w - b.w;
        mse_acc += e0 * e0 + e1 * e1 + e2 * e2 + e3 * e3;
        if (i < limit4) {
            float4 c = in4[i + t4];
            float d0 = a.x - c.x, d1 = a.y - c.y, d2 = a.z - c.z, d3 = a.w - c.w;
            dif_acc += d0 * d0 + d1 * d1 + d2 * d2 + d3 * d3;
        }
    }

    // scalar tail (n % 4, and diff-region boundary not 4-aligned) — handled by first threads
    {
        const float* in = (const float*)in4;
        const float* tg = (const float*)tg4;
        long long gid = (long long)blockIdx.x * blockDim.x + threadIdx.x;
        // mse tail
        long long tail_start = n4 << 2;
        long long idx = tail_start + gid;
        if (idx < n) {
            float e = in[idx] - tg[idx];
            mse_acc += e * e;
        }
        // diff tail (elements in [limit4*4, limit))
        long long dtail_start = limit4 << 2;
        long long didx = dtail_start + gid;
        if (didx < limit) {
            float d = in[didx] - in[didx + T];
            dif_acc += d * d;
        }
    }

    // wave-64 butterfly reduce
    #pragma unroll
    for (int off = 32; off > 0; off >>= 1) {
        mse_acc += __shfl_down(mse_acc, off, 64);
        dif_acc += __shfl_down(dif_acc, off, 64);
    }

    __shared__ float s_m[4];
    __shared__ float s_d[4];
    const int wave = threadIdx.x >> 6;
    if ((threadIdx.x & 63) == 0) {
        s_m[wave] = mse_acc;
        s_d[wave] = dif_acc;
    }
    __syncthreads();
    if (threadIdx.x == 0) {
        double m = (double)s_m[0] + (double)s_m[1] + (double)s_m[2] + (double)s_m[3];
        double d = (double)s_d[0] + (double)s_d[1] + (double)s_d[2] + (double)s_d[3];
        atomicAdd(&ws[0], m);
        atomicAdd(&ws[1], d);
    }
}

__global__ void cyclic_finalize_kernel(const double* __restrict__ ws,
                                       const int* __restrict__ pN,
                                       float* __restrict__ out,
                                       long long n)
{
    if (threadIdx.x == 0 && blockIdx.x == 0) {
        double mse = ws[0] / (double)n;
        double nom = (pN[0] != 1) ? (LAMDA * sqrt(ws[1])) : 0.0;
        out[0] = (float)(mse + nom);
    }
}

extern "C" void kernel_launch(void* const* d_in, const int* in_sizes, int n_in,
                              void* d_out, int out_size, void* d_ws, size_t ws_size,
                              hipStream_t stream) {
    const float* input  = (const float*)d_in[0];
    const float* target = (const float*)d_in[1];
    const int*   pT     = (const int*)d_in[2];
    const int*   pN     = (const int*)d_in[3];
    float* out = (float*)d_out;
    double* ws = (double*)d_ws;

    const long long n = (long long)in_sizes[0];

    // zero the two double accumulators (d_ws is poisoned 0xAA before every call)
    hipMemsetAsync(ws, 0, 2 * sizeof(double), stream);

    const int block = 256;
    const int grid = 2048;  // 512K threads, 8 float4 iters/thread over 4M float4s
    cyclic_reduce_kernel<<<grid, block, 0, stream>>>(
        (const float4*)input, (const float4*)target, pT, pN, n, ws);

    cyclic_finalize_kernel<<<1, 64, 0, stream>>>(ws, pN, out, n);
}